// Round 6
// baseline (168.467 us; speedup 1.0000x reference)
//
#include <hip/hip_runtime.h>
#include <hip/hip_bf16.h>
#include <cstddef>

// All-fp32 pipeline (round-1-proven numerics), rebuilt for speed:
//  - kFgemm: fp32 128x128x32 tiled GEMM, 8x8 register micro-tiles,
//            both GEMMs in one launch (z = 0: enc@W1, z = 1: dec@W2 + b)
//  - kBattn: fused tanh-score/softmax/context, 4 decoder steps per block
//            (one per wave, shared batch -> 4x L1 reuse, no barriers)

#define SCALE2L2E 2.8853900817779268f  /* 2*log2(e) for fast tanh */
#define LOG2E 1.4426950408889634f

// ---------------- kFgemm: C_z = A_z @ W_z (+bias_z) ----------------------
// A [2048,512] row-major, W [512,512] row-major, C [2048,512].
__global__ __launch_bounds__(256) void kFgemm(
    const float* __restrict__ A0, const float* __restrict__ A1,
    const float* __restrict__ W1, const float* __restrict__ W2,
    const float* __restrict__ bv,
    float* __restrict__ C0, float* __restrict__ C1)
{
    const int z = blockIdx.z;
    const float* __restrict__ A = z ? A1 : A0;
    const float* __restrict__ W = z ? W2 : W1;
    float* __restrict__ C = z ? C1 : C0;

    __shared__ float As[32][132];   // [k][m], +4 pad
    __shared__ float Bs[32][132];   // [k][n], +4 pad

    const int tid = threadIdx.x;
    const int tx = tid & 15;        // 16 col-groups
    const int ty = tid >> 4;        // 16 row-groups
    const int rowB = blockIdx.y * 128;
    const int colB = blockIdx.x * 128;

    // staging coords
    const int ar  = tid >> 1;           // A row 0..127
    const int ak0 = (tid & 1) * 16;     // A k-chunk base
    const int brk = tid >> 3;           // B k-row 0..31
    const int bn0 = (tid & 7) * 16;     // B n-chunk base

    float acc[8][8] = {};

    for (int k0 = 0; k0 < 512; k0 += 32) {
        float4 ag[4], bg[4];
        #pragma unroll
        for (int j = 0; j < 4; ++j)
            ag[j] = *(const float4*)&A[(size_t)(rowB + ar) * 512 + k0 + ak0 + 4 * j];
        #pragma unroll
        for (int j = 0; j < 4; ++j)
            bg[j] = *(const float4*)&W[(size_t)(k0 + brk) * 512 + colB + bn0 + 4 * j];

        __syncthreads();   // previous iteration's readers done
        #pragma unroll
        for (int j = 0; j < 4; ++j) {
            As[ak0 + 4 * j + 0][ar] = ag[j].x;
            As[ak0 + 4 * j + 1][ar] = ag[j].y;
            As[ak0 + 4 * j + 2][ar] = ag[j].z;
            As[ak0 + 4 * j + 3][ar] = ag[j].w;
            *(float4*)&Bs[brk][bn0 + 4 * j] = bg[j];
        }
        __syncthreads();

        #pragma unroll
        for (int k = 0; k < 32; ++k) {
            float am[8], bn[8];
            *(float4*)&am[0] = *(const float4*)&As[k][ty * 8];
            *(float4*)&am[4] = *(const float4*)&As[k][ty * 8 + 4];
            *(float4*)&bn[0] = *(const float4*)&Bs[k][tx * 8];
            *(float4*)&bn[4] = *(const float4*)&Bs[k][tx * 8 + 4];
            #pragma unroll
            for (int i = 0; i < 8; ++i)
                #pragma unroll
                for (int j = 0; j < 8; ++j)
                    acc[i][j] = fmaf(am[i], bn[j], acc[i][j]);
        }
    }

    // epilogue (+bias for z==1)
    float bb[8];
    #pragma unroll
    for (int j = 0; j < 8; ++j)
        bb[j] = z ? bv[colB + tx * 8 + j] : 0.0f;
    #pragma unroll
    for (int i = 0; i < 8; ++i) {
        const int row = rowB + ty * 8 + i;
        float o[8];
        #pragma unroll
        for (int j = 0; j < 8; ++j) o[j] = acc[i][j] + bb[j];
        *(float4*)&C[(size_t)row * 512 + colB + tx * 8]     = *(float4*)&o[0];
        *(float4*)&C[(size_t)row * 512 + colB + tx * 8 + 4] = *(float4*)&o[4];
    }
}

// ---------------- kBattn: fused score/softmax/context --------------------
// Grid (T/4, B); block = 4 waves. Wave wv owns t = tg*4 + wv; all waves
// share batch b so W1hs/enc row reads hit L1. No block-wide barriers.
// logit = sum_e V_e * tanh(x1+x2) with tanh(x) = 1 - 2*rcp(exp2(x*S)+1).
__global__ __launch_bounds__(256) void kBattn(
    const float* __restrict__ X1,   // [B*S,512] = enc@W1
    const float* __restrict__ X2b,  // [B*T,512] = dec@W2 + b
    const float* __restrict__ V,    // [512]
    const float* __restrict__ enc,  // [B*S,512]
    float* __restrict__ ctx,        // [B*T,512]
    float* __restrict__ attnw)      // [B*T,128]
{
    const int b  = blockIdx.y;
    const int tg = blockIdx.x;      // 0..31
    const int tid  = threadIdx.x;
    const int lane = tid & 63;
    const int wv   = tid >> 6;
    const int bt = b * 128 + tg * 4 + wv;

    __shared__ float sm[4][128];

    const float4* xp = (const float4*)(X2b + (size_t)bt * 512);
    const float4  c0 = xp[lane * 2], c1 = xp[lane * 2 + 1];
    const float4* vp = (const float4*)V;
    const float4  v0 = vp[lane * 2], v1 = vp[lane * 2 + 1];
    const float4 n0 = make_float4(-2.f * v0.x, -2.f * v0.y, -2.f * v0.z, -2.f * v0.w);
    const float4 n1 = make_float4(-2.f * v1.x, -2.f * v1.y, -2.f * v1.z, -2.f * v1.w);
    const float vsum = v0.x + v0.y + v0.z + v0.w + v1.x + v1.y + v1.z + v1.w;

    const float* base = X1 + (size_t)b * 128 * 512;
    for (int s = 0; s < 128; ++s) {
        const float4* ap = (const float4*)(base + (size_t)s * 512);
        const float4 x0 = ap[lane * 2], x1 = ap[lane * 2 + 1];
        float acc = vsum;
        acc += n0.x * __builtin_amdgcn_rcpf(__builtin_amdgcn_exp2f((x0.x + c0.x) * SCALE2L2E) + 1.0f);
        acc += n0.y * __builtin_amdgcn_rcpf(__builtin_amdgcn_exp2f((x0.y + c0.y) * SCALE2L2E) + 1.0f);
        acc += n0.z * __builtin_amdgcn_rcpf(__builtin_amdgcn_exp2f((x0.z + c0.z) * SCALE2L2E) + 1.0f);
        acc += n0.w * __builtin_amdgcn_rcpf(__builtin_amdgcn_exp2f((x0.w + c0.w) * SCALE2L2E) + 1.0f);
        acc += n1.x * __builtin_amdgcn_rcpf(__builtin_amdgcn_exp2f((x1.x + c1.x) * SCALE2L2E) + 1.0f);
        acc += n1.y * __builtin_amdgcn_rcpf(__builtin_amdgcn_exp2f((x1.y + c1.y) * SCALE2L2E) + 1.0f);
        acc += n1.z * __builtin_amdgcn_rcpf(__builtin_amdgcn_exp2f((x1.z + c1.z) * SCALE2L2E) + 1.0f);
        acc += n1.w * __builtin_amdgcn_rcpf(__builtin_amdgcn_exp2f((x1.w + c1.w) * SCALE2L2E) + 1.0f);
        #pragma unroll
        for (int off = 32; off >= 1; off >>= 1)
            acc += __shfl_xor(acc, off);
        if (lane == 0) sm[wv][s] = acc;
    }
    // per-wave data only -> no barrier needed

    const float l0 = sm[wv][lane], l1 = sm[wv][lane + 64];
    float m = fmaxf(l0, l1);
    #pragma unroll
    for (int off = 32; off >= 1; off >>= 1)
        m = fmaxf(m, __shfl_xor(m, off));
    const float e0 = __builtin_amdgcn_exp2f((l0 - m) * LOG2E);
    const float e1 = __builtin_amdgcn_exp2f((l1 - m) * LOG2E);
    float sum = e0 + e1;
    #pragma unroll
    for (int off = 32; off >= 1; off >>= 1)
        sum += __shfl_xor(sum, off);
    const float inv = __builtin_amdgcn_rcpf(sum);
    const float weight0 = e0 * inv, weight1 = e1 * inv;
    sm[wv][lane]      = weight0;
    sm[wv][lane + 64] = weight1;
    attnw[(size_t)bt * 128 + lane]      = weight0;
    attnw[(size_t)bt * 128 + lane + 64] = weight1;

    float4 a0 = {0.f, 0.f, 0.f, 0.f}, a1 = {0.f, 0.f, 0.f, 0.f};
    const float* encb = enc + (size_t)b * 128 * 512;
    for (int s = 0; s < 128; ++s) {
        const float wgt = sm[wv][s];
        const float4* ep = (const float4*)(encb + (size_t)s * 512);
        const float4 q0 = ep[lane * 2], q1 = ep[lane * 2 + 1];
        a0.x = fmaf(wgt, q0.x, a0.x); a0.y = fmaf(wgt, q0.y, a0.y);
        a0.z = fmaf(wgt, q0.z, a0.z); a0.w = fmaf(wgt, q0.w, a0.w);
        a1.x = fmaf(wgt, q1.x, a1.x); a1.y = fmaf(wgt, q1.y, a1.y);
        a1.z = fmaf(wgt, q1.z, a1.z); a1.w = fmaf(wgt, q1.w, a1.w);
    }
    float4* cp = (float4*)(ctx + (size_t)bt * 512);
    cp[lane * 2]     = a0;
    cp[lane * 2 + 1] = a1;
}

extern "C" void kernel_launch(void* const* d_in, const int* in_sizes, int n_in,
                              void* d_out, int out_size, void* d_ws, size_t ws_size,
                              hipStream_t stream) {
    const float* enc = (const float*)d_in[0];   // [16,128,512]
    const float* dec = (const float*)d_in[1];   // [16,128,512]
    const float* W1  = (const float*)d_in[2];   // [512,512]
    const float* W2  = (const float*)d_in[3];   // [512,512]
    const float* bv  = (const float*)d_in[4];   // [512]
    const float* V   = (const float*)d_in[5];   // [512]

    float* ctx   = (float*)d_out;                        // [16,128,512]
    float* attnw = (float*)d_out + (size_t)16 * 128 * 512; // [16,128,128]

    float* ws0 = (float*)d_ws;                  // enc@W1        [2048,512]
    float* ws1 = ws0 + (size_t)2048 * 512;      // dec@W2 + b    [2048,512]

    kFgemm<<<dim3(4, 16, 2), dim3(256), 0, stream>>>(
        enc, dec, W1, W2, bv, ws0, ws1);
    kBattn<<<dim3(32, 16), dim3(256), 0, stream>>>(
        ws0, ws1, V, enc, ctx, attnw);
}

// Round 7
// 90.950 us; speedup vs baseline: 1.8523x; 1.8523x over previous
//
#include <hip/hip_runtime.h>
#include <hip/hip_bf16.h>
#include <cstddef>

// Pipeline:
//  kSgemm: split-bf16 (hi+lo) MFMA GEMM, 3 terms: ah*wh + al*wh + ah*wl.
//          64x64 tiles, BK=32, inline W-transpose staging, 512 blocks.
//          Epilogue folds bias (z==1) and the 2*log2(e) tanh prescale.
//  kCattn: round-1-proven 2048-block fused score/softmax/context with
//          op-dieted score loop (3 VALU + 2 trans per element).

constexpr int nBt = 16, nSq = 128, nTq = 128, nEd = 512;

typedef __attribute__((ext_vector_type(4))) float f32x4;
typedef __attribute__((ext_vector_type(8))) short s16x8;

#define PRESCALE 2.8853900817779268f  /* 2*log2(e) */
#define LOG2E 1.4426950408889634f

__device__ __forceinline__ unsigned short to_bf(float f) {
    unsigned u = __builtin_bit_cast(unsigned, f);
    return (unsigned short)((u + 0x7FFFu + ((u >> 16) & 1u)) >> 16);  // RNE
}
__device__ __forceinline__ float from_bf(unsigned short h) {
    unsigned u = ((unsigned)h) << 16;
    return __builtin_bit_cast(float, u);
}

// ---- kSgemm: C_z = (A_z @ W_z [+bias]) * PRESCALE -----------------------
// A [2048,512] f32 row-major, W [512,512] f32 row-major (k-major -> n,k
// transpose happens in LDS staging). Grid (512/64, 2048/64, 2).
__global__ __launch_bounds__(256) void kSgemm(
    const float* __restrict__ A0, const float* __restrict__ A1,
    const float* __restrict__ W1, const float* __restrict__ W2,
    const float* __restrict__ bias,
    float* __restrict__ C0, float* __restrict__ C1)
{
    const int z = blockIdx.z;
    const float* __restrict__ A = z ? A1 : A0;
    const float* __restrict__ W = z ? W2 : W1;
    float* __restrict__ C = z ? C1 : C0;

    __shared__ unsigned short sAh[64][40];   // [m][k] +8 pad
    __shared__ unsigned short sAl[64][40];
    __shared__ unsigned short sBh[64][40];   // [n][k] +8 pad
    __shared__ unsigned short sBl[64][40];

    const int tid  = threadIdx.x;
    const int lane = tid & 63;
    const int wv   = tid >> 6;
    const int wm = (wv >> 1) * 32;      // wave tile 32x32 in 2x2 wave grid
    const int wn = (wv & 1) * 32;
    const int rowB = blockIdx.y * 64;
    const int colB = blockIdx.x * 64;

    const int ar = tid >> 2, ak = (tid & 3) * 8;   // A stage: 8 f32/thread
    const int rk = tid >> 3, n0 = (tid & 7) * 8;   // W stage: 8 f32/thread

    f32x4 acc[2][2] = {};
    const int l15 = lane & 15;
    const int kh  = lane >> 4;

    for (int k0 = 0; k0 < nEd; k0 += 32) {
        const float4 ga0 = *(const float4*)&A[(size_t)(rowB + ar) * nEd + k0 + ak];
        const float4 ga1 = *(const float4*)&A[(size_t)(rowB + ar) * nEd + k0 + ak + 4];
        const float4 gw0 = *(const float4*)&W[(size_t)(k0 + rk) * nEd + colB + n0];
        const float4 gw1 = *(const float4*)&W[(size_t)(k0 + rk) * nEd + colB + n0 + 4];

        __syncthreads();   // previous iteration's fragment readers done
        {
            const float av[8] = {ga0.x, ga0.y, ga0.z, ga0.w,
                                 ga1.x, ga1.y, ga1.z, ga1.w};
            unsigned short h[8], l[8];
            #pragma unroll
            for (int i = 0; i < 8; ++i) {
                h[i] = to_bf(av[i]);
                l[i] = to_bf(av[i] - from_bf(h[i]));  // exact residual
            }
            *(ushort4*)&sAh[ar][ak]     = *(ushort4*)&h[0];
            *(ushort4*)&sAh[ar][ak + 4] = *(ushort4*)&h[4];
            *(ushort4*)&sAl[ar][ak]     = *(ushort4*)&l[0];
            *(ushort4*)&sAl[ar][ak + 4] = *(ushort4*)&l[4];

            const float wvv[8] = {gw0.x, gw0.y, gw0.z, gw0.w,
                                  gw1.x, gw1.y, gw1.z, gw1.w};
            #pragma unroll
            for (int i = 0; i < 8; ++i) {            // transpose: [n][k]
                const unsigned short wh = to_bf(wvv[i]);
                sBh[n0 + i][rk] = wh;
                sBl[n0 + i][rk] = to_bf(wvv[i] - from_bf(wh));
            }
        }
        __syncthreads();

        s16x8 fAh[2], fAl[2], fBh[2], fBl[2];
        #pragma unroll
        for (int mi = 0; mi < 2; ++mi) {
            fAh[mi] = *(const s16x8*)&sAh[wm + mi * 16 + l15][kh * 8];
            fAl[mi] = *(const s16x8*)&sAl[wm + mi * 16 + l15][kh * 8];
        }
        #pragma unroll
        for (int ni = 0; ni < 2; ++ni) {
            fBh[ni] = *(const s16x8*)&sBh[wn + ni * 16 + l15][kh * 8];
            fBl[ni] = *(const s16x8*)&sBl[wn + ni * 16 + l15][kh * 8];
        }
        #pragma unroll
        for (int mi = 0; mi < 2; ++mi)
            #pragma unroll
            for (int ni = 0; ni < 2; ++ni) {
                f32x4 a = acc[mi][ni];
                a = __builtin_amdgcn_mfma_f32_16x16x32_bf16(fAh[mi], fBh[ni], a, 0, 0, 0);
                a = __builtin_amdgcn_mfma_f32_16x16x32_bf16(fAl[mi], fBh[ni], a, 0, 0, 0);
                a = __builtin_amdgcn_mfma_f32_16x16x32_bf16(fAh[mi], fBl[ni], a, 0, 0, 0);
                acc[mi][ni] = a;
            }
    }

    // epilogue: C = (acc [+bias]) * PRESCALE
    // C/D map (16x16x32): col = lane&15, row = (lane>>4)*4 + reg
    #pragma unroll
    for (int ni = 0; ni < 2; ++ni) {
        const int col = colB + wn + ni * 16 + l15;
        const float bval = z ? bias[col] : 0.0f;
        #pragma unroll
        for (int mi = 0; mi < 2; ++mi) {
            #pragma unroll
            for (int r = 0; r < 4; ++r) {
                const int row = rowB + wm + mi * 16 + kh * 4 + r;
                C[(size_t)row * nEd + col] = (acc[mi][ni][r] + bval) * PRESCALE;
            }
        }
    }
}

// ---- kCattn: fused score/softmax/context, one block per (b,t) -----------
// Round-1-proven structure (2048 blocks, occupancy ~60%). Score loop diet:
// logit = vsum + sum_e n_e * rcp(exp2(arg_e)+1), n = -2V, args pre-scaled.
__global__ __launch_bounds__(256) void kCattn(
    const float* __restrict__ X1,   // [B*S,E] = enc@W1, prescaled
    const float* __restrict__ X2b,  // [B*T,E] = dec@W2+b, prescaled
    const float* __restrict__ V,    // [E]
    const float* __restrict__ enc,  // [B*S,E]
    float* __restrict__ ctx,        // [B*T,E]
    float* __restrict__ attnw)      // [B*T,S]
{
    const int bt = blockIdx.x;
    const int b  = bt >> 7;
    const int tid  = threadIdx.x;
    const int lane = tid & 63;
    const int w    = tid >> 6;

    __shared__ float sm[nSq];

    const float4* xp = (const float4*)(X2b + (size_t)bt * nEd);
    const float4  c0 = xp[lane * 2], c1 = xp[lane * 2 + 1];
    const float4* vp = (const float4*)V;
    const float4  v0 = vp[lane * 2], v1 = vp[lane * 2 + 1];
    const float4 n0 = make_float4(-2.f * v0.x, -2.f * v0.y, -2.f * v0.z, -2.f * v0.w);
    const float4 n1 = make_float4(-2.f * v1.x, -2.f * v1.y, -2.f * v1.z, -2.f * v1.w);
    const float vsum = v0.x + v0.y + v0.z + v0.w + v1.x + v1.y + v1.z + v1.w;

    const float* base = X1 + (size_t)b * nSq * nEd;
    #pragma unroll 2
    for (int s = w; s < nSq; s += 4) {
        const float4* ap = (const float4*)(base + (size_t)s * nEd);
        const float4 x0 = ap[lane * 2], x1 = ap[lane * 2 + 1];
        float acc = vsum;
        acc += n0.x * __builtin_amdgcn_rcpf(__builtin_amdgcn_exp2f(x0.x + c0.x) + 1.0f);
        acc += n0.y * __builtin_amdgcn_rcpf(__builtin_amdgcn_exp2f(x0.y + c0.y) + 1.0f);
        acc += n0.z * __builtin_amdgcn_rcpf(__builtin_amdgcn_exp2f(x0.z + c0.z) + 1.0f);
        acc += n0.w * __builtin_amdgcn_rcpf(__builtin_amdgcn_exp2f(x0.w + c0.w) + 1.0f);
        acc += n1.x * __builtin_amdgcn_rcpf(__builtin_amdgcn_exp2f(x1.x + c1.x) + 1.0f);
        acc += n1.y * __builtin_amdgcn_rcpf(__builtin_amdgcn_exp2f(x1.y + c1.y) + 1.0f);
        acc += n1.z * __builtin_amdgcn_rcpf(__builtin_amdgcn_exp2f(x1.z + c1.z) + 1.0f);
        acc += n1.w * __builtin_amdgcn_rcpf(__builtin_amdgcn_exp2f(x1.w + c1.w) + 1.0f);
        #pragma unroll
        for (int off = 32; off >= 1; off >>= 1)
            acc += __shfl_xor(acc, off);
        if (lane == 0) sm[s] = acc;
    }
    __syncthreads();

    if (w == 0) {
        const float l0 = sm[lane], l1 = sm[lane + 64];
        float m = fmaxf(l0, l1);
        #pragma unroll
        for (int off = 32; off >= 1; off >>= 1)
            m = fmaxf(m, __shfl_xor(m, off));
        const float e0 = __builtin_amdgcn_exp2f((l0 - m) * LOG2E);
        const float e1 = __builtin_amdgcn_exp2f((l1 - m) * LOG2E);
        float sum = e0 + e1;
        #pragma unroll
        for (int off = 32; off >= 1; off >>= 1)
            sum += __shfl_xor(sum, off);
        const float inv = __builtin_amdgcn_rcpf(sum);
        const float wv0 = e0 * inv, wv1 = e1 * inv;
        sm[lane]      = wv0;
        sm[lane + 64] = wv1;
        attnw[(size_t)bt * nSq + lane]      = wv0;
        attnw[(size_t)bt * nSq + lane + 64] = wv1;
    }
    __syncthreads();

    // context: thread owns e = tid*2, tid*2+1 (float2)
    float2 a = {0.f, 0.f};
    const float* encb = enc + (size_t)b * nSq * nEd + tid * 2;
    #pragma unroll 4
    for (int s = 0; s < nSq; ++s) {
        const float wgt = sm[s];
        const float2 ev = *(const float2*)&encb[(size_t)s * nEd];
        a.x = fmaf(wgt, ev.x, a.x);
        a.y = fmaf(wgt, ev.y, a.y);
    }
    *(float2*)&ctx[(size_t)bt * nEd + tid * 2] = a;
}

extern "C" void kernel_launch(void* const* d_in, const int* in_sizes, int n_in,
                              void* d_out, int out_size, void* d_ws, size_t ws_size,
                              hipStream_t stream) {
    const float* enc = (const float*)d_in[0];   // [16,128,512]
    const float* dec = (const float*)d_in[1];   // [16,128,512]
    const float* W1  = (const float*)d_in[2];   // [512,512]
    const float* W2  = (const float*)d_in[3];   // [512,512]
    const float* bv  = (const float*)d_in[4];   // [512]
    const float* V   = (const float*)d_in[5];   // [512]

    float* ctx   = (float*)d_out;                           // [16,128,512]
    float* attnw = (float*)d_out + (size_t)nBt * nTq * nEd; // [16,128,128]

    float* ws0 = (float*)d_ws;                    // (enc@W1)*PRESCALE
    float* ws1 = ws0 + (size_t)nBt * nSq * nEd;   // (dec@W2+b)*PRESCALE

    kSgemm<<<dim3(nEd / 64, (nBt * nSq) / 64, 2), dim3(256), 0, stream>>>(
        enc, dec, W1, W2, bv, ws0, ws1);
    kCattn<<<dim3(nBt * nTq), dim3(256), 0, stream>>>(
        ws0, ws1, V, enc, ctx, attnw);
}

// Round 8
// 88.074 us; speedup vs baseline: 1.9128x; 1.0327x over previous
//
#include <hip/hip_runtime.h>
#include <hip/hip_bf16.h>
#include <cstddef>

// Pipeline (5 phases, 4 kernels):
//  kWprep  : W1,W2 -> WT split-bf16 [term][z][n][k] in d_out ctx region (2MB)
//  kMgemm  : split-bf16 3-term MFMA GEMM, BK=64, ws0=(enc@W1)*PS, ws1=(dec@W2+b)*PS
//  kLogits : scores with 4-t sharing per wave (X1 traffic /4), logits -> d_out attn region
//  kSoftCtx: r1/r7-proven softmax + vector context per (b,t), in-place weights

constexpr int nBt = 16, nSq = 128, nTq = 128, nEd = 512;

typedef __attribute__((ext_vector_type(4))) float f32x4;
typedef __attribute__((ext_vector_type(8))) short s16x8;

#define PRESCALE 2.8853900817779268f  /* 2*log2(e) */
#define LOG2E 1.4426950408889634f

__device__ __forceinline__ unsigned short to_bf(float f) {
    unsigned u = __builtin_bit_cast(unsigned, f);
    return (unsigned short)((u + 0x7FFFu + ((u >> 16) & 1u)) >> 16);  // RNE
}
__device__ __forceinline__ float from_bf(unsigned short h) {
    unsigned u = ((unsigned)h) << 16;
    return __builtin_bit_cast(float, u);
}

// ---- kWprep: WT[term][z][n][k] = split_bf16(W_z[k][n]) ------------------
__global__ __launch_bounds__(256) void kWprep(
    const float* __restrict__ W1, const float* __restrict__ W2,
    unsigned short* __restrict__ WT)
{
    const int z = blockIdx.z;
    const float* W = z ? W2 : W1;
    __shared__ float tl[32][33];
    const int r  = threadIdx.x >> 3;
    const int c4 = (threadIdx.x & 7) * 4;
    const int kB = blockIdx.y * 32;
    const int nB = blockIdx.x * 32;
    const float4 v = *(const float4*)&W[(size_t)(kB + r) * nEd + nB + c4];
    tl[r][c4 + 0] = v.x; tl[r][c4 + 1] = v.y;
    tl[r][c4 + 2] = v.z; tl[r][c4 + 3] = v.w;
    __syncthreads();
    unsigned short hh[4], ll[4];
    #pragma unroll
    for (int i = 0; i < 4; ++i) {
        const float x = tl[c4 + i][r];
        hh[i] = to_bf(x);
        ll[i] = to_bf(x - from_bf(hh[i]));   // exact residual
    }
    const size_t o = ((size_t)z * nEd + nB + r) * nEd + kB + c4;
    *(ushort4*)&WT[o] = *(ushort4*)hh;
    *(ushort4*)&WT[(size_t)2 * nEd * nEd + o] = *(ushort4*)ll;
}

// ---- kMgemm: C_z = (A_z @ W_z [+bias]) * PRESCALE, BK=64 ----------------
// 64x64 tiles, 4 waves 2x2 (wave tile 32x32), 3-term split-bf16.
__global__ __launch_bounds__(256) void kMgemm(
    const float* __restrict__ A0, const float* __restrict__ A1,
    const unsigned short* __restrict__ WT, const float* __restrict__ bias,
    float* __restrict__ C0, float* __restrict__ C1)
{
    const int z = blockIdx.z;
    const float* __restrict__ A = z ? A1 : A0;
    const unsigned short* __restrict__ Wh = WT + (size_t)z * nEd * nEd;
    const unsigned short* __restrict__ Wl = Wh + (size_t)2 * nEd * nEd;
    float* __restrict__ C = z ? C1 : C0;

    __shared__ unsigned short sAh[64][72];   // [m][k] +8 pad
    __shared__ unsigned short sAl[64][72];
    __shared__ unsigned short sBh[64][72];   // [n][k] +8 pad
    __shared__ unsigned short sBl[64][72];

    const int tid  = threadIdx.x;
    const int lane = tid & 63;
    const int wv   = tid >> 6;
    const int wm = (wv >> 1) * 32;
    const int wn = (wv & 1) * 32;
    const int rowB = blockIdx.y * 64;
    const int colB = blockIdx.x * 64;

    const int ar = tid >> 2, ak = (tid & 3) * 16;   // A: 16 f32/thread
    const int wr = tid >> 2, wk = (tid & 3) * 16;   // W: 16 ushort/thread/plane

    f32x4 acc[2][2] = {};
    const int l15 = lane & 15;
    const int kh  = lane >> 4;

    for (int k0 = 0; k0 < nEd; k0 += 64) {
        float4 ga[4];
        #pragma unroll
        for (int j = 0; j < 4; ++j)
            ga[j] = *(const float4*)&A[(size_t)(rowB + ar) * nEd + k0 + ak + 4 * j];
        const size_t wo = (size_t)(colB + wr) * nEd + k0 + wk;
        const s16x8 gh0 = *(const s16x8*)&Wh[wo];
        const s16x8 gh1 = *(const s16x8*)&Wh[wo + 8];
        const s16x8 gl0 = *(const s16x8*)&Wl[wo];
        const s16x8 gl1 = *(const s16x8*)&Wl[wo + 8];

        __syncthreads();   // previous iteration's fragment readers done
        #pragma unroll
        for (int j = 0; j < 4; ++j) {
            const float a4[4] = {ga[j].x, ga[j].y, ga[j].z, ga[j].w};
            unsigned short h[4], l[4];
            #pragma unroll
            for (int i = 0; i < 4; ++i) {
                h[i] = to_bf(a4[i]);
                l[i] = to_bf(a4[i] - from_bf(h[i]));
            }
            *(ushort4*)&sAh[ar][ak + 4 * j] = *(ushort4*)h;
            *(ushort4*)&sAl[ar][ak + 4 * j] = *(ushort4*)l;
        }
        *(s16x8*)&sBh[wr][wk]     = gh0;
        *(s16x8*)&sBh[wr][wk + 8] = gh1;
        *(s16x8*)&sBl[wr][wk]     = gl0;
        *(s16x8*)&sBl[wr][wk + 8] = gl1;
        __syncthreads();

        #pragma unroll
        for (int kk = 0; kk < 2; ++kk) {
            s16x8 fAh[2], fAl[2], fBh[2], fBl[2];
            #pragma unroll
            for (int mi = 0; mi < 2; ++mi) {
                fAh[mi] = *(const s16x8*)&sAh[wm + mi * 16 + l15][kk * 32 + kh * 8];
                fAl[mi] = *(const s16x8*)&sAl[wm + mi * 16 + l15][kk * 32 + kh * 8];
            }
            #pragma unroll
            for (int ni = 0; ni < 2; ++ni) {
                fBh[ni] = *(const s16x8*)&sBh[wn + ni * 16 + l15][kk * 32 + kh * 8];
                fBl[ni] = *(const s16x8*)&sBl[wn + ni * 16 + l15][kk * 32 + kh * 8];
            }
            #pragma unroll
            for (int mi = 0; mi < 2; ++mi)
                #pragma unroll
                for (int ni = 0; ni < 2; ++ni) {
                    f32x4 a = acc[mi][ni];
                    a = __builtin_amdgcn_mfma_f32_16x16x32_bf16(fAh[mi], fBh[ni], a, 0, 0, 0);
                    a = __builtin_amdgcn_mfma_f32_16x16x32_bf16(fAl[mi], fBh[ni], a, 0, 0, 0);
                    a = __builtin_amdgcn_mfma_f32_16x16x32_bf16(fAh[mi], fBl[ni], a, 0, 0, 0);
                    acc[mi][ni] = a;
                }
        }
    }

    // epilogue (r7-proven C/D map): col = l15, row = kh*4 + reg
    #pragma unroll
    for (int ni = 0; ni < 2; ++ni) {
        const int col = colB + wn + ni * 16 + l15;
        const float bval = z ? bias[col] : 0.0f;
        #pragma unroll
        for (int mi = 0; mi < 2; ++mi) {
            #pragma unroll
            for (int r = 0; r < 4; ++r) {
                const int row = rowB + wm + mi * 16 + kh * 4 + r;
                C[(size_t)row * nEd + col] = (acc[mi][ni][r] + bval) * PRESCALE;
            }
        }
    }
}

// ---- kLogits: logits with 4-t sharing per wave --------------------------
// Grid (4 sg, 32 tg, 16 b), 4 waves. Wave w: s in [sg*32+w*8, +8), t in
// [tg*4, +4). Each X1 row load feeds 4 t -> X1 L2 traffic / 4.
// logit[b,t,s] = vsum + sum_e n_e * rcp(exp2(x1+x2)+1)  (args prescaled)
__global__ __launch_bounds__(256) void kLogits(
    const float* __restrict__ X1,   // [B*S,E] prescaled
    const float* __restrict__ X2b,  // [B*T,E] prescaled, +bias
    const float* __restrict__ V,    // [E]
    float* __restrict__ lg)         // [B*T,S]
{
    const int sg = blockIdx.x, tg = blockIdx.y, b = blockIdx.z;
    const int tid  = threadIdx.x;
    const int lane = tid & 63;
    const int w    = tid >> 6;
    const int s0 = sg * 32 + w * 8;
    const int t0 = tg * 4;

    const float4* vp = (const float4*)V;
    const float4  v0 = vp[lane * 2], v1 = vp[lane * 2 + 1];
    const float4 n0 = make_float4(-2.f * v0.x, -2.f * v0.y, -2.f * v0.z, -2.f * v0.w);
    const float4 n1 = make_float4(-2.f * v1.x, -2.f * v1.y, -2.f * v1.z, -2.f * v1.w);
    const float vsum = v0.x + v0.y + v0.z + v0.w + v1.x + v1.y + v1.z + v1.w;

    float4 c0[4], c1[4];
    #pragma unroll
    for (int i = 0; i < 4; ++i) {
        const float4* xp = (const float4*)(X2b + ((size_t)b * nTq + t0 + i) * nEd);
        c0[i] = xp[lane * 2];
        c1[i] = xp[lane * 2 + 1];
    }

    for (int si = 0; si < 8; ++si) {
        const int s = s0 + si;
        const float4* ap = (const float4*)(X1 + ((size_t)b * nSq + s) * nEd);
        const float4 x0 = ap[lane * 2], x1 = ap[lane * 2 + 1];
        float acc[4];
        #pragma unroll
        for (int t = 0; t < 4; ++t) {
            float a = vsum;
            a += n0.x * __builtin_amdgcn_rcpf(__builtin_amdgcn_exp2f(x0.x + c0[t].x) + 1.0f);
            a += n0.y * __builtin_amdgcn_rcpf(__builtin_amdgcn_exp2f(x0.y + c0[t].y) + 1.0f);
            a += n0.z * __builtin_amdgcn_rcpf(__builtin_amdgcn_exp2f(x0.z + c0[t].z) + 1.0f);
            a += n0.w * __builtin_amdgcn_rcpf(__builtin_amdgcn_exp2f(x0.w + c0[t].w) + 1.0f);
            a += n1.x * __builtin_amdgcn_rcpf(__builtin_amdgcn_exp2f(x1.x + c1[t].x) + 1.0f);
            a += n1.y * __builtin_amdgcn_rcpf(__builtin_amdgcn_exp2f(x1.y + c1[t].y) + 1.0f);
            a += n1.z * __builtin_amdgcn_rcpf(__builtin_amdgcn_exp2f(x1.z + c1[t].z) + 1.0f);
            a += n1.w * __builtin_amdgcn_rcpf(__builtin_amdgcn_exp2f(x1.w + c1[t].w) + 1.0f);
            acc[t] = a;
        }
        #pragma unroll
        for (int t = 0; t < 4; ++t) {
            float a = acc[t];
            #pragma unroll
            for (int off = 32; off >= 1; off >>= 1)
                a += __shfl_xor(a, off);
            if (lane == 0)
                lg[((size_t)b * nTq + t0 + t) * nSq + s] = a;
        }
    }
}

// ---- kSoftCtx: softmax (in-place on logits region) + vector context -----
__global__ __launch_bounds__(256) void kSoftCtx(
    const float* __restrict__ enc,  // [B*S,E]
    float* __restrict__ ctx,        // [B*T,E]
    float* __restrict__ attnw)      // [B*T,S], holds logits on entry
{
    const int bt = blockIdx.x;
    const int b  = bt >> 7;
    const int tid  = threadIdx.x;
    const int lane = tid & 63;
    const int w    = tid >> 6;

    __shared__ float sm[nSq];
    if (tid < nSq) sm[tid] = attnw[(size_t)bt * nSq + tid];
    __syncthreads();

    if (w == 0) {
        const float l0 = sm[lane], l1 = sm[lane + 64];
        float m = fmaxf(l0, l1);
        #pragma unroll
        for (int off = 32; off >= 1; off >>= 1)
            m = fmaxf(m, __shfl_xor(m, off));
        const float e0 = __builtin_amdgcn_exp2f((l0 - m) * LOG2E);
        const float e1 = __builtin_amdgcn_exp2f((l1 - m) * LOG2E);
        float sum = e0 + e1;
        #pragma unroll
        for (int off = 32; off >= 1; off >>= 1)
            sum += __shfl_xor(sum, off);
        const float inv = __builtin_amdgcn_rcpf(sum);
        const float wv0 = e0 * inv, wv1 = e1 * inv;
        sm[lane]      = wv0;
        sm[lane + 64] = wv1;
        attnw[(size_t)bt * nSq + lane]      = wv0;
        attnw[(size_t)bt * nSq + lane + 64] = wv1;
    }
    __syncthreads();

    float2 a = {0.f, 0.f};
    const float* encb = enc + (size_t)b * nSq * nEd + tid * 2;
    #pragma unroll 4
    for (int s = 0; s < nSq; ++s) {
        const float wgt = sm[s];
        const float2 ev = *(const float2*)&encb[(size_t)s * nEd];
        a.x = fmaf(wgt, ev.x, a.x);
        a.y = fmaf(wgt, ev.y, a.y);
    }
    *(float2*)&ctx[(size_t)bt * nEd + tid * 2] = a;
}

extern "C" void kernel_launch(void* const* d_in, const int* in_sizes, int n_in,
                              void* d_out, int out_size, void* d_ws, size_t ws_size,
                              hipStream_t stream) {
    const float* enc = (const float*)d_in[0];   // [16,128,512]
    const float* dec = (const float*)d_in[1];   // [16,128,512]
    const float* W1  = (const float*)d_in[2];   // [512,512]
    const float* W2  = (const float*)d_in[3];   // [512,512]
    const float* bv  = (const float*)d_in[4];   // [512]
    const float* V   = (const float*)d_in[5];   // [512]

    float* ctx   = (float*)d_out;                           // [16,128,512] 4MB
    float* attnw = (float*)d_out + (size_t)nBt * nTq * nEd; // [16,128,128] 1MB

    // WT (2MB) in ctx region — dead before kSoftCtx writes ctx (r2-proven).
    unsigned short* WT = (unsigned short*)d_out;

    float* ws0 = (float*)d_ws;                    // (enc@W1)*PRESCALE
    float* ws1 = ws0 + (size_t)nBt * nSq * nEd;   // (dec@W2+b)*PRESCALE

    kWprep<<<dim3(nEd / 32, nEd / 32, 2), dim3(256), 0, stream>>>(W1, W2, WT);
    kMgemm<<<dim3(nEd / 64, (nBt * nSq) / 64, 2), dim3(256), 0, stream>>>(
        enc, dec, WT, bv, ws0, ws1);
    kLogits<<<dim3(4, 32, nBt), dim3(256), 0, stream>>>(ws0, ws1, V, attnw);
    kSoftCtx<<<dim3(nBt * nTq), dim3(256), 0, stream>>>(enc, ctx, attnw);
}

// Round 9
// 68.222 us; speedup vs baseline: 2.4694x; 1.2910x over previous
//
#include <hip/hip_runtime.h>
#include <hip/hip_bf16.h>
#include <cstddef>

// Pipeline (6 kernels):
//  kWprep : W1,W2 -> split-bf16 WT [term][z][n][k] in d_out ctx region (2MB)
//  kMgemm : split-bf16 3-term MFMA GEMM -> ws0=(enc@W1)*PS, ws1=(dec@W2+b)*PS
//  kLogits: scores, 4-t sharing per wave; logits -> d_out attn region
//  kEncT  : enc -> bf16 transpose encT[b][e][s] in ws0 (dead after kLogits)
//  kSoft  : softmax per (b,t): f32 weights -> attnw, bf16 weights -> scratch
//  kCtxMM : MFMA batched context GEMM ctx[b] = attn_bf[b] @ encT[b]

constexpr int nBt = 16, nSq = 128, nTq = 128, nEd = 512;

typedef __attribute__((ext_vector_type(4))) float f32x4;
typedef __attribute__((ext_vector_type(8))) short s16x8;

#define PRESCALE 2.8853900817779268f  /* 2*log2(e) */
#define LOG2E 1.4426950408889634f

__device__ __forceinline__ unsigned short to_bf(float f) {
    unsigned u = __builtin_bit_cast(unsigned, f);
    return (unsigned short)((u + 0x7FFFu + ((u >> 16) & 1u)) >> 16);  // RNE
}
__device__ __forceinline__ float from_bf(unsigned short h) {
    unsigned u = ((unsigned)h) << 16;
    return __builtin_bit_cast(float, u);
}

// ---- kWprep: WT[term][z][n][k] = split_bf16(W_z[k][n]) ------------------
__global__ __launch_bounds__(256) void kWprep(
    const float* __restrict__ W1, const float* __restrict__ W2,
    unsigned short* __restrict__ WT)
{
    const int z = blockIdx.z;
    const float* W = z ? W2 : W1;
    __shared__ float tl[32][33];
    const int r  = threadIdx.x >> 3;
    const int c4 = (threadIdx.x & 7) * 4;
    const int kB = blockIdx.y * 32;
    const int nB = blockIdx.x * 32;
    const float4 v = *(const float4*)&W[(size_t)(kB + r) * nEd + nB + c4];
    tl[r][c4 + 0] = v.x; tl[r][c4 + 1] = v.y;
    tl[r][c4 + 2] = v.z; tl[r][c4 + 3] = v.w;
    __syncthreads();
    unsigned short hh[4], ll[4];
    #pragma unroll
    for (int i = 0; i < 4; ++i) {
        const float x = tl[c4 + i][r];
        hh[i] = to_bf(x);
        ll[i] = to_bf(x - from_bf(hh[i]));   // exact residual
    }
    const size_t o = ((size_t)z * nEd + nB + r) * nEd + kB + c4;
    *(ushort4*)&WT[o] = *(ushort4*)hh;
    *(ushort4*)&WT[(size_t)2 * nEd * nEd + o] = *(ushort4*)ll;
}

// ---- kMgemm: C_z = (A_z @ W_z [+bias]) * PRESCALE, BK=64 (r8-proven) ----
__global__ __launch_bounds__(256) void kMgemm(
    const float* __restrict__ A0, const float* __restrict__ A1,
    const unsigned short* __restrict__ WT, const float* __restrict__ bias,
    float* __restrict__ C0, float* __restrict__ C1)
{
    const int z = blockIdx.z;
    const float* __restrict__ A = z ? A1 : A0;
    const unsigned short* __restrict__ Wh = WT + (size_t)z * nEd * nEd;
    const unsigned short* __restrict__ Wl = Wh + (size_t)2 * nEd * nEd;
    float* __restrict__ C = z ? C1 : C0;

    __shared__ unsigned short sAh[64][72];
    __shared__ unsigned short sAl[64][72];
    __shared__ unsigned short sBh[64][72];
    __shared__ unsigned short sBl[64][72];

    const int tid  = threadIdx.x;
    const int lane = tid & 63;
    const int wv   = tid >> 6;
    const int wm = (wv >> 1) * 32;
    const int wn = (wv & 1) * 32;
    const int rowB = blockIdx.y * 64;
    const int colB = blockIdx.x * 64;

    const int ar = tid >> 2, ak = (tid & 3) * 16;
    const int wr = tid >> 2, wk = (tid & 3) * 16;

    f32x4 acc[2][2] = {};
    const int l15 = lane & 15;
    const int kh  = lane >> 4;

    for (int k0 = 0; k0 < nEd; k0 += 64) {
        float4 ga[4];
        #pragma unroll
        for (int j = 0; j < 4; ++j)
            ga[j] = *(const float4*)&A[(size_t)(rowB + ar) * nEd + k0 + ak + 4 * j];
        const size_t wo = (size_t)(colB + wr) * nEd + k0 + wk;
        const s16x8 gh0 = *(const s16x8*)&Wh[wo];
        const s16x8 gh1 = *(const s16x8*)&Wh[wo + 8];
        const s16x8 gl0 = *(const s16x8*)&Wl[wo];
        const s16x8 gl1 = *(const s16x8*)&Wl[wo + 8];

        __syncthreads();
        #pragma unroll
        for (int j = 0; j < 4; ++j) {
            const float a4[4] = {ga[j].x, ga[j].y, ga[j].z, ga[j].w};
            unsigned short h[4], l[4];
            #pragma unroll
            for (int i = 0; i < 4; ++i) {
                h[i] = to_bf(a4[i]);
                l[i] = to_bf(a4[i] - from_bf(h[i]));
            }
            *(ushort4*)&sAh[ar][ak + 4 * j] = *(ushort4*)h;
            *(ushort4*)&sAl[ar][ak + 4 * j] = *(ushort4*)l;
        }
        *(s16x8*)&sBh[wr][wk]     = gh0;
        *(s16x8*)&sBh[wr][wk + 8] = gh1;
        *(s16x8*)&sBl[wr][wk]     = gl0;
        *(s16x8*)&sBl[wr][wk + 8] = gl1;
        __syncthreads();

        #pragma unroll
        for (int kk = 0; kk < 2; ++kk) {
            s16x8 fAh[2], fAl[2], fBh[2], fBl[2];
            #pragma unroll
            for (int mi = 0; mi < 2; ++mi) {
                fAh[mi] = *(const s16x8*)&sAh[wm + mi * 16 + l15][kk * 32 + kh * 8];
                fAl[mi] = *(const s16x8*)&sAl[wm + mi * 16 + l15][kk * 32 + kh * 8];
            }
            #pragma unroll
            for (int ni = 0; ni < 2; ++ni) {
                fBh[ni] = *(const s16x8*)&sBh[wn + ni * 16 + l15][kk * 32 + kh * 8];
                fBl[ni] = *(const s16x8*)&sBl[wn + ni * 16 + l15][kk * 32 + kh * 8];
            }
            #pragma unroll
            for (int mi = 0; mi < 2; ++mi)
                #pragma unroll
                for (int ni = 0; ni < 2; ++ni) {
                    f32x4 a = acc[mi][ni];
                    a = __builtin_amdgcn_mfma_f32_16x16x32_bf16(fAh[mi], fBh[ni], a, 0, 0, 0);
                    a = __builtin_amdgcn_mfma_f32_16x16x32_bf16(fAl[mi], fBh[ni], a, 0, 0, 0);
                    a = __builtin_amdgcn_mfma_f32_16x16x32_bf16(fAh[mi], fBl[ni], a, 0, 0, 0);
                    acc[mi][ni] = a;
                }
        }
    }

    #pragma unroll
    for (int ni = 0; ni < 2; ++ni) {
        const int col = colB + wn + ni * 16 + l15;
        const float bval = z ? bias[col] : 0.0f;
        #pragma unroll
        for (int mi = 0; mi < 2; ++mi) {
            #pragma unroll
            for (int r = 0; r < 4; ++r) {
                const int row = rowB + wm + mi * 16 + kh * 4 + r;
                C[(size_t)row * nEd + col] = (acc[mi][ni][r] + bval) * PRESCALE;
            }
        }
    }
}

// ---- kLogits: scores, 4-t sharing per wave (r8-proven) ------------------
__global__ __launch_bounds__(256) void kLogits(
    const float* __restrict__ X1,   // [B*S,E] prescaled
    const float* __restrict__ X2b,  // [B*T,E] prescaled, +bias
    const float* __restrict__ V,    // [E]
    float* __restrict__ lg)         // [B*T,S]
{
    const int sg = blockIdx.x, tg = blockIdx.y, b = blockIdx.z;
    const int tid  = threadIdx.x;
    const int lane = tid & 63;
    const int w    = tid >> 6;
    const int s0 = sg * 32 + w * 8;
    const int t0 = tg * 4;

    const float4* vp = (const float4*)V;
    const float4  v0 = vp[lane * 2], v1 = vp[lane * 2 + 1];
    const float4 n0 = make_float4(-2.f * v0.x, -2.f * v0.y, -2.f * v0.z, -2.f * v0.w);
    const float4 n1 = make_float4(-2.f * v1.x, -2.f * v1.y, -2.f * v1.z, -2.f * v1.w);
    const float vsum = v0.x + v0.y + v0.z + v0.w + v1.x + v1.y + v1.z + v1.w;

    float4 c0[4], c1[4];
    #pragma unroll
    for (int i = 0; i < 4; ++i) {
        const float4* xp = (const float4*)(X2b + ((size_t)b * nTq + t0 + i) * nEd);
        c0[i] = xp[lane * 2];
        c1[i] = xp[lane * 2 + 1];
    }

    for (int si = 0; si < 8; ++si) {
        const int s = s0 + si;
        const float4* ap = (const float4*)(X1 + ((size_t)b * nSq + s) * nEd);
        const float4 x0 = ap[lane * 2], x1 = ap[lane * 2 + 1];
        float acc[4];
        #pragma unroll
        for (int t = 0; t < 4; ++t) {
            float a = vsum;
            a += n0.x * __builtin_amdgcn_rcpf(__builtin_amdgcn_exp2f(x0.x + c0[t].x) + 1.0f);
            a += n0.y * __builtin_amdgcn_rcpf(__builtin_amdgcn_exp2f(x0.y + c0[t].y) + 1.0f);
            a += n0.z * __builtin_amdgcn_rcpf(__builtin_amdgcn_exp2f(x0.z + c0[t].z) + 1.0f);
            a += n0.w * __builtin_amdgcn_rcpf(__builtin_amdgcn_exp2f(x0.w + c0[t].w) + 1.0f);
            a += n1.x * __builtin_amdgcn_rcpf(__builtin_amdgcn_exp2f(x1.x + c1[t].x) + 1.0f);
            a += n1.y * __builtin_amdgcn_rcpf(__builtin_amdgcn_exp2f(x1.y + c1[t].y) + 1.0f);
            a += n1.z * __builtin_amdgcn_rcpf(__builtin_amdgcn_exp2f(x1.z + c1[t].z) + 1.0f);
            a += n1.w * __builtin_amdgcn_rcpf(__builtin_amdgcn_exp2f(x1.w + c1[t].w) + 1.0f);
            acc[t] = a;
        }
        #pragma unroll
        for (int t = 0; t < 4; ++t) {
            float a = acc[t];
            #pragma unroll
            for (int off = 32; off >= 1; off >>= 1)
                a += __shfl_xor(a, off);
            if (lane == 0)
                lg[((size_t)b * nTq + t0 + t) * nSq + s] = a;
        }
    }
}

// ---- kEncT: encT[b][e][s] = bf16(enc[b][s][e]) --------------------------
__global__ __launch_bounds__(256) void kEncT(
    const float* __restrict__ enc, unsigned short* __restrict__ encT)
{
    const int b = blockIdx.z;
    __shared__ float tl[32][33];
    const int r  = threadIdx.x >> 3;
    const int c4 = (threadIdx.x & 7) * 4;
    const int sB = blockIdx.y * 32;
    const int eB = blockIdx.x * 32;
    const float4 v = *(const float4*)&enc[((size_t)b * nSq + sB + r) * nEd + eB + c4];
    tl[r][c4 + 0] = v.x; tl[r][c4 + 1] = v.y;
    tl[r][c4 + 2] = v.z; tl[r][c4 + 3] = v.w;
    __syncthreads();
    unsigned short o[4];
    #pragma unroll
    for (int i = 0; i < 4; ++i) o[i] = to_bf(tl[c4 + i][r]);
    *(ushort4*)&encT[((size_t)b * nEd + eB + r) * nSq + sB + c4] = *(ushort4*)o;
}

// ---- kSoft: softmax per (b,t); f32 weights + bf16 weights ---------------
__global__ __launch_bounds__(256) void kSoft(
    float* __restrict__ attnw,            // in: logits, out: weights
    unsigned short* __restrict__ attnbf)  // [B*T,S] bf16 weights
{
    const int bt = blockIdx.x * 4 + (threadIdx.x >> 6);
    const int lane = threadIdx.x & 63;
    const float l0 = attnw[(size_t)bt * nSq + lane];
    const float l1 = attnw[(size_t)bt * nSq + lane + 64];
    float m = fmaxf(l0, l1);
    #pragma unroll
    for (int off = 32; off >= 1; off >>= 1)
        m = fmaxf(m, __shfl_xor(m, off));
    const float e0 = __builtin_amdgcn_exp2f((l0 - m) * LOG2E);
    const float e1 = __builtin_amdgcn_exp2f((l1 - m) * LOG2E);
    float sum = e0 + e1;
    #pragma unroll
    for (int off = 32; off >= 1; off >>= 1)
        sum += __shfl_xor(sum, off);
    const float inv = __builtin_amdgcn_rcpf(sum);
    const float w0 = e0 * inv, w1 = e1 * inv;
    attnw[(size_t)bt * nSq + lane]      = w0;
    attnw[(size_t)bt * nSq + lane + 64] = w1;
    attnbf[(size_t)bt * nSq + lane]      = to_bf(w0);
    attnbf[(size_t)bt * nSq + lane + 64] = to_bf(w1);
}

// ---- kCtxMM: ctx[b] = attn_bf[b] @ encT[b]^T (batched MFMA GEMM) --------
// Grid (8 e-tiles of 64, 4 t-tiles of 32, 16 b). K = S = 128, single stage.
__global__ __launch_bounds__(256) void kCtxMM(
    const unsigned short* __restrict__ attnbf,  // [B*T,S]
    const unsigned short* __restrict__ encT,    // [B*E,S]
    float* __restrict__ ctx)                    // [B*T,E]
{
    const int b  = blockIdx.z;
    const int tB = blockIdx.y * 32;
    const int eB = blockIdx.x * 64;

    __shared__ unsigned short sA[32][136];   // [t][s] +8 pad
    __shared__ unsigned short sB[64][136];   // [e][s] +8 pad

    const int tid  = threadIdx.x;
    const int lane = tid & 63;
    const int w    = tid >> 6;
    const int wm = (w >> 1) * 16;   // t
    const int wn = (w & 1) * 32;    // e
    const int l15 = lane & 15;
    const int kh  = lane >> 4;

    {   // stage A: 32x128 ushorts (16/thread)
        const int r = tid >> 3, c = (tid & 7) * 16;
        const size_t o = ((size_t)b * nTq + tB + r) * nSq + c;
        *(s16x8*)&sA[r][c]     = *(const s16x8*)&attnbf[o];
        *(s16x8*)&sA[r][c + 8] = *(const s16x8*)&attnbf[o + 8];
    }
    {   // stage B: 64x128 ushorts (32/thread)
        const int r = tid >> 2, c = (tid & 3) * 32;
        const size_t o = ((size_t)b * nEd + eB + r) * nSq + c;
        *(s16x8*)&sB[r][c]      = *(const s16x8*)&encT[o];
        *(s16x8*)&sB[r][c + 8]  = *(const s16x8*)&encT[o + 8];
        *(s16x8*)&sB[r][c + 16] = *(const s16x8*)&encT[o + 16];
        *(s16x8*)&sB[r][c + 24] = *(const s16x8*)&encT[o + 24];
    }
    __syncthreads();

    f32x4 acc[2] = {};
    #pragma unroll
    for (int kk = 0; kk < 4; ++kk) {
        const s16x8 fA = *(const s16x8*)&sA[wm + l15][kk * 32 + kh * 8];
        #pragma unroll
        for (int ni = 0; ni < 2; ++ni) {
            const s16x8 fB = *(const s16x8*)&sB[wn + ni * 16 + l15][kk * 32 + kh * 8];
            acc[ni] = __builtin_amdgcn_mfma_f32_16x16x32_bf16(fA, fB, acc[ni], 0, 0, 0);
        }
    }

    // D map (r7/r8-proven): col(n=e) = l15, row(m=t) = kh*4 + r
    #pragma unroll
    for (int ni = 0; ni < 2; ++ni) {
        const int e = eB + wn + ni * 16 + l15;
        #pragma unroll
        for (int r = 0; r < 4; ++r) {
            const int t = tB + wm + kh * 4 + r;
            ctx[((size_t)b * nTq + t) * nEd + e] = acc[ni][r];
        }
    }
}

extern "C" void kernel_launch(void* const* d_in, const int* in_sizes, int n_in,
                              void* d_out, int out_size, void* d_ws, size_t ws_size,
                              hipStream_t stream) {
    const float* enc = (const float*)d_in[0];   // [16,128,512]
    const float* dec = (const float*)d_in[1];   // [16,128,512]
    const float* W1  = (const float*)d_in[2];   // [512,512]
    const float* W2  = (const float*)d_in[3];   // [512,512]
    const float* bv  = (const float*)d_in[4];   // [512]
    const float* V   = (const float*)d_in[5];   // [512]

    float* ctx   = (float*)d_out;                           // [16,128,512] 4MB
    float* attnw = (float*)d_out + (size_t)nBt * nTq * nEd; // [16,128,128] 1MB

    // WT (2MB) in ctx region — dead before kCtxMM writes ctx.
    unsigned short* WT = (unsigned short*)d_out;

    float* ws0 = (float*)d_ws;                    // (enc@W1)*PRESCALE, 4MB
    float* ws1 = ws0 + (size_t)nBt * nSq * nEd;   // (dec@W2+b)*PRESCALE, 4MB
    // After kLogits, ws0 region is reused:
    unsigned short* encT   = (unsigned short*)d_ws;                    // 2MB
    unsigned short* attnbf = (unsigned short*)((char*)d_ws + 2*1024*1024); // 512KB

    kWprep<<<dim3(nEd / 32, nEd / 32, 2), dim3(256), 0, stream>>>(W1, W2, WT);
    kMgemm<<<dim3(nEd / 64, (nBt * nSq) / 64, 2), dim3(256), 0, stream>>>(
        enc, dec, WT, bv, ws0, ws1);
    kLogits<<<dim3(4, 32, nBt), dim3(256), 0, stream>>>(ws0, ws1, V, attnw);
    kEncT<<<dim3(nEd / 32, nSq / 32, nBt), dim3(256), 0, stream>>>(enc, encT);
    kSoft<<<dim3((nBt * nTq) / 4), dim3(256), 0, stream>>>(attnw, attnbf);
    kCtxMM<<<dim3(nEd / 64, nTq / 32, nBt), dim3(256), 0, stream>>>(
        attnbf, encT, ctx);
}

// Round 10
// 59.404 us; speedup vs baseline: 2.8359x; 1.1484x over previous
//
#include <hip/hip_runtime.h>
#include <hip/hip_bf16.h>
#include <cstddef>

// Pipeline (6 kernels):
//  kWprep : W1,W2 -> split-bf16 WT [term][z][n][k] in d_out ctx region (2MB)
//  kMgemm : split-bf16 3-term MFMA GEMM; epilogue stores EXP2 of prescaled
//           activations: ws0=exp2((enc@W1)*PS), ws1=exp2((dec@W2+b)*PS)
//  kLogits: factored-sigmoid scores: denom = ex1*ec + 1 -> exactly 1 trans
//           (rcp) per element; 4-t sharing per wave
//  kEncT  : enc -> bf16 transpose encT[b][e][s] in ws0 (dead after kLogits)
//  kSoft  : softmax per (b,t): f32 weights -> attnw, bf16 weights -> scratch
//  kCtxMM : MFMA batched context GEMM ctx[b] = attn_bf[b] @ encT[b]

constexpr int nBt = 16, nSq = 128, nTq = 128, nEd = 512;

typedef __attribute__((ext_vector_type(4))) float f32x4;
typedef __attribute__((ext_vector_type(8))) short s16x8;

#define PRESCALE 2.8853900817779268f  /* 2*log2(e) */
#define LOG2E 1.4426950408889634f

__device__ __forceinline__ unsigned short to_bf(float f) {
    unsigned u = __builtin_bit_cast(unsigned, f);
    return (unsigned short)((u + 0x7FFFu + ((u >> 16) & 1u)) >> 16);  // RNE
}
__device__ __forceinline__ float from_bf(unsigned short h) {
    unsigned u = ((unsigned)h) << 16;
    return __builtin_bit_cast(float, u);
}

// ---- kWprep: WT[term][z][n][k] = split_bf16(W_z[k][n]) ------------------
__global__ __launch_bounds__(256) void kWprep(
    const float* __restrict__ W1, const float* __restrict__ W2,
    unsigned short* __restrict__ WT)
{
    const int z = blockIdx.z;
    const float* W = z ? W2 : W1;
    __shared__ float tl[32][33];
    const int r  = threadIdx.x >> 3;
    const int c4 = (threadIdx.x & 7) * 4;
    const int kB = blockIdx.y * 32;
    const int nB = blockIdx.x * 32;
    const float4 v = *(const float4*)&W[(size_t)(kB + r) * nEd + nB + c4];
    tl[r][c4 + 0] = v.x; tl[r][c4 + 1] = v.y;
    tl[r][c4 + 2] = v.z; tl[r][c4 + 3] = v.w;
    __syncthreads();
    unsigned short hh[4], ll[4];
    #pragma unroll
    for (int i = 0; i < 4; ++i) {
        const float x = tl[c4 + i][r];
        hh[i] = to_bf(x);
        ll[i] = to_bf(x - from_bf(hh[i]));   // exact residual
    }
    const size_t o = ((size_t)z * nEd + nB + r) * nEd + kB + c4;
    *(ushort4*)&WT[o] = *(ushort4*)hh;
    *(ushort4*)&WT[(size_t)2 * nEd * nEd + o] = *(ushort4*)ll;
}

// ---- kMgemm: C_z = exp2((A_z @ W_z [+bias]) * PRESCALE), BK=64 ----------
__global__ __launch_bounds__(256) void kMgemm(
    const float* __restrict__ A0, const float* __restrict__ A1,
    const unsigned short* __restrict__ WT, const float* __restrict__ bias,
    float* __restrict__ C0, float* __restrict__ C1)
{
    const int z = blockIdx.z;
    const float* __restrict__ A = z ? A1 : A0;
    const unsigned short* __restrict__ Wh = WT + (size_t)z * nEd * nEd;
    const unsigned short* __restrict__ Wl = Wh + (size_t)2 * nEd * nEd;
    float* __restrict__ C = z ? C1 : C0;

    __shared__ unsigned short sAh[64][72];
    __shared__ unsigned short sAl[64][72];
    __shared__ unsigned short sBh[64][72];
    __shared__ unsigned short sBl[64][72];

    const int tid  = threadIdx.x;
    const int lane = tid & 63;
    const int wv   = tid >> 6;
    const int wm = (wv >> 1) * 32;
    const int wn = (wv & 1) * 32;
    const int rowB = blockIdx.y * 64;
    const int colB = blockIdx.x * 64;

    const int ar = tid >> 2, ak = (tid & 3) * 16;
    const int wr = tid >> 2, wk = (tid & 3) * 16;

    f32x4 acc[2][2] = {};
    const int l15 = lane & 15;
    const int kh  = lane >> 4;

    for (int k0 = 0; k0 < nEd; k0 += 64) {
        float4 ga[4];
        #pragma unroll
        for (int j = 0; j < 4; ++j)
            ga[j] = *(const float4*)&A[(size_t)(rowB + ar) * nEd + k0 + ak + 4 * j];
        const size_t wo = (size_t)(colB + wr) * nEd + k0 + wk;
        const s16x8 gh0 = *(const s16x8*)&Wh[wo];
        const s16x8 gh1 = *(const s16x8*)&Wh[wo + 8];
        const s16x8 gl0 = *(const s16x8*)&Wl[wo];
        const s16x8 gl1 = *(const s16x8*)&Wl[wo + 8];

        __syncthreads();
        #pragma unroll
        for (int j = 0; j < 4; ++j) {
            const float a4[4] = {ga[j].x, ga[j].y, ga[j].z, ga[j].w};
            unsigned short h[4], l[4];
            #pragma unroll
            for (int i = 0; i < 4; ++i) {
                h[i] = to_bf(a4[i]);
                l[i] = to_bf(a4[i] - from_bf(h[i]));
            }
            *(ushort4*)&sAh[ar][ak + 4 * j] = *(ushort4*)h;
            *(ushort4*)&sAl[ar][ak + 4 * j] = *(ushort4*)l;
        }
        *(s16x8*)&sBh[wr][wk]     = gh0;
        *(s16x8*)&sBh[wr][wk + 8] = gh1;
        *(s16x8*)&sBl[wr][wk]     = gl0;
        *(s16x8*)&sBl[wr][wk + 8] = gl1;
        __syncthreads();

        #pragma unroll
        for (int kk = 0; kk < 2; ++kk) {
            s16x8 fAh[2], fAl[2], fBh[2], fBl[2];
            #pragma unroll
            for (int mi = 0; mi < 2; ++mi) {
                fAh[mi] = *(const s16x8*)&sAh[wm + mi * 16 + l15][kk * 32 + kh * 8];
                fAl[mi] = *(const s16x8*)&sAl[wm + mi * 16 + l15][kk * 32 + kh * 8];
            }
            #pragma unroll
            for (int ni = 0; ni < 2; ++ni) {
                fBh[ni] = *(const s16x8*)&sBh[wn + ni * 16 + l15][kk * 32 + kh * 8];
                fBl[ni] = *(const s16x8*)&sBl[wn + ni * 16 + l15][kk * 32 + kh * 8];
            }
            #pragma unroll
            for (int mi = 0; mi < 2; ++mi)
                #pragma unroll
                for (int ni = 0; ni < 2; ++ni) {
                    f32x4 a = acc[mi][ni];
                    a = __builtin_amdgcn_mfma_f32_16x16x32_bf16(fAh[mi], fBh[ni], a, 0, 0, 0);
                    a = __builtin_amdgcn_mfma_f32_16x16x32_bf16(fAl[mi], fBh[ni], a, 0, 0, 0);
                    a = __builtin_amdgcn_mfma_f32_16x16x32_bf16(fAh[mi], fBl[ni], a, 0, 0, 0);
                    acc[mi][ni] = a;
                }
        }
    }

    // epilogue: store exp2 of prescaled activation (factored-sigmoid prep)
    #pragma unroll
    for (int ni = 0; ni < 2; ++ni) {
        const int col = colB + wn + ni * 16 + l15;
        const float bval = z ? bias[col] : 0.0f;
        #pragma unroll
        for (int mi = 0; mi < 2; ++mi) {
            #pragma unroll
            for (int r = 0; r < 4; ++r) {
                const int row = rowB + wm + mi * 16 + kh * 4 + r;
                C[(size_t)row * nEd + col] =
                    __builtin_amdgcn_exp2f((acc[mi][ni][r] + bval) * PRESCALE);
            }
        }
    }
}

// ---- kLogits: factored-sigmoid scores, 4-t sharing per wave -------------
// X1e/X2e hold exp2 of prescaled activations. Per element:
//   logit += nv_e * rcp(ex1_e * ec_{t,e} + 1)   (1 trans + 3 VALU)
__global__ __launch_bounds__(256) void kLogits(
    const float* __restrict__ X1e,  // [B*S,E] exp2'd
    const float* __restrict__ X2e,  // [B*T,E] exp2'd (bias folded)
    const float* __restrict__ V,    // [E]
    float* __restrict__ lg)         // [B*T,S]
{
    const int sg = blockIdx.x, tg = blockIdx.y, b = blockIdx.z;
    const int tid  = threadIdx.x;
    const int lane = tid & 63;
    const int w    = tid >> 6;
    const int s0 = sg * 32 + w * 8;
    const int t0 = tg * 4;

    const float4* vp = (const float4*)V;
    const float4  v0 = vp[lane * 2], v1 = vp[lane * 2 + 1];
    const float4 n0 = make_float4(-2.f * v0.x, -2.f * v0.y, -2.f * v0.z, -2.f * v0.w);
    const float4 n1 = make_float4(-2.f * v1.x, -2.f * v1.y, -2.f * v1.z, -2.f * v1.w);
    const float vsum = v0.x + v0.y + v0.z + v0.w + v1.x + v1.y + v1.z + v1.w;

    float4 c0[4], c1[4];   // exp2(c) per local t
    #pragma unroll
    for (int i = 0; i < 4; ++i) {
        const float4* xp = (const float4*)(X2e + ((size_t)b * nTq + t0 + i) * nEd);
        c0[i] = xp[lane * 2];
        c1[i] = xp[lane * 2 + 1];
    }

    for (int si = 0; si < 8; ++si) {
        const int s = s0 + si;
        const float4* ap = (const float4*)(X1e + ((size_t)b * nSq + s) * nEd);
        const float4 x0 = ap[lane * 2], x1 = ap[lane * 2 + 1];
        float acc[4];
        #pragma unroll
        for (int t = 0; t < 4; ++t) {
            float a = vsum;
            a += n0.x * __builtin_amdgcn_rcpf(x0.x * c0[t].x + 1.0f);
            a += n0.y * __builtin_amdgcn_rcpf(x0.y * c0[t].y + 1.0f);
            a += n0.z * __builtin_amdgcn_rcpf(x0.z * c0[t].z + 1.0f);
            a += n0.w * __builtin_amdgcn_rcpf(x0.w * c0[t].w + 1.0f);
            a += n1.x * __builtin_amdgcn_rcpf(x1.x * c1[t].x + 1.0f);
            a += n1.y * __builtin_amdgcn_rcpf(x1.y * c1[t].y + 1.0f);
            a += n1.z * __builtin_amdgcn_rcpf(x1.z * c1[t].z + 1.0f);
            a += n1.w * __builtin_amdgcn_rcpf(x1.w * c1[t].w + 1.0f);
            acc[t] = a;
        }
        #pragma unroll
        for (int t = 0; t < 4; ++t) {
            float a = acc[t];
            #pragma unroll
            for (int off = 32; off >= 1; off >>= 1)
                a += __shfl_xor(a, off);
            if (lane == 0)
                lg[((size_t)b * nTq + t0 + t) * nSq + s] = a;
        }
    }
}

// ---- kEncT: encT[b][e][s] = bf16(enc[b][s][e]) --------------------------
__global__ __launch_bounds__(256) void kEncT(
    const float* __restrict__ enc, unsigned short* __restrict__ encT)
{
    const int b = blockIdx.z;
    __shared__ float tl[32][33];
    const int r  = threadIdx.x >> 3;
    const int c4 = (threadIdx.x & 7) * 4;
    const int sB = blockIdx.y * 32;
    const int eB = blockIdx.x * 32;
    const float4 v = *(const float4*)&enc[((size_t)b * nSq + sB + r) * nEd + eB + c4];
    tl[r][c4 + 0] = v.x; tl[r][c4 + 1] = v.y;
    tl[r][c4 + 2] = v.z; tl[r][c4 + 3] = v.w;
    __syncthreads();
    unsigned short o[4];
    #pragma unroll
    for (int i = 0; i < 4; ++i) o[i] = to_bf(tl[c4 + i][r]);
    *(ushort4*)&encT[((size_t)b * nEd + eB + r) * nSq + sB + c4] = *(ushort4*)o;
}

// ---- kSoft: softmax per (b,t); f32 weights + bf16 weights ---------------
__global__ __launch_bounds__(256) void kSoft(
    float* __restrict__ attnw,            // in: logits, out: weights
    unsigned short* __restrict__ attnbf)  // [B*T,S] bf16 weights
{
    const int bt = blockIdx.x * 4 + (threadIdx.x >> 6);
    const int lane = threadIdx.x & 63;
    const float l0 = attnw[(size_t)bt * nSq + lane];
    const float l1 = attnw[(size_t)bt * nSq + lane + 64];
    float m = fmaxf(l0, l1);
    #pragma unroll
    for (int off = 32; off >= 1; off >>= 1)
        m = fmaxf(m, __shfl_xor(m, off));
    const float e0 = __builtin_amdgcn_exp2f((l0 - m) * LOG2E);
    const float e1 = __builtin_amdgcn_exp2f((l1 - m) * LOG2E);
    float sum = e0 + e1;
    #pragma unroll
    for (int off = 32; off >= 1; off >>= 1)
        sum += __shfl_xor(sum, off);
    const float inv = __builtin_amdgcn_rcpf(sum);
    const float w0 = e0 * inv, w1 = e1 * inv;
    attnw[(size_t)bt * nSq + lane]      = w0;
    attnw[(size_t)bt * nSq + lane + 64] = w1;
    attnbf[(size_t)bt * nSq + lane]      = to_bf(w0);
    attnbf[(size_t)bt * nSq + lane + 64] = to_bf(w1);
}

// ---- kCtxMM: ctx[b] = attn_bf[b] @ encT[b]^T (batched MFMA GEMM) --------
__global__ __launch_bounds__(256) void kCtxMM(
    const unsigned short* __restrict__ attnbf,  // [B*T,S]
    const unsigned short* __restrict__ encT,    // [B*E,S]
    float* __restrict__ ctx)                    // [B*T,E]
{
    const int b  = blockIdx.z;
    const int tB = blockIdx.y * 32;
    const int eB = blockIdx.x * 64;

    __shared__ unsigned short sA[32][136];
    __shared__ unsigned short sB[64][136];

    const int tid  = threadIdx.x;
    const int lane = tid & 63;
    const int w    = tid >> 6;
    const int wm = (w >> 1) * 16;
    const int wn = (w & 1) * 32;
    const int l15 = lane & 15;
    const int kh  = lane >> 4;

    {
        const int r = tid >> 3, c = (tid & 7) * 16;
        const size_t o = ((size_t)b * nTq + tB + r) * nSq + c;
        *(s16x8*)&sA[r][c]     = *(const s16x8*)&attnbf[o];
        *(s16x8*)&sA[r][c + 8] = *(const s16x8*)&attnbf[o + 8];
    }
    {
        const int r = tid >> 2, c = (tid & 3) * 32;
        const size_t o = ((size_t)b * nEd + eB + r) * nSq + c;
        *(s16x8*)&sB[r][c]      = *(const s16x8*)&encT[o];
        *(s16x8*)&sB[r][c + 8]  = *(const s16x8*)&encT[o + 8];
        *(s16x8*)&sB[r][c + 16] = *(const s16x8*)&encT[o + 16];
        *(s16x8*)&sB[r][c + 24] = *(const s16x8*)&encT[o + 24];
    }
    __syncthreads();

    f32x4 acc[2] = {};
    #pragma unroll
    for (int kk = 0; kk < 4; ++kk) {
        const s16x8 fA = *(const s16x8*)&sA[wm + l15][kk * 32 + kh * 8];
        #pragma unroll
        for (int ni = 0; ni < 2; ++ni) {
            const s16x8 fB = *(const s16x8*)&sB[wn + ni * 16 + l15][kk * 32 + kh * 8];
            acc[ni] = __builtin_amdgcn_mfma_f32_16x16x32_bf16(fA, fB, acc[ni], 0, 0, 0);
        }
    }

    #pragma unroll
    for (int ni = 0; ni < 2; ++ni) {
        const int e = eB + wn + ni * 16 + l15;
        #pragma unroll
        for (int r = 0; r < 4; ++r) {
            const int t = tB + wm + kh * 4 + r;
            ctx[((size_t)b * nTq + t) * nEd + e] = acc[ni][r];
        }
    }
}

extern "C" void kernel_launch(void* const* d_in, const int* in_sizes, int n_in,
                              void* d_out, int out_size, void* d_ws, size_t ws_size,
                              hipStream_t stream) {
    const float* enc = (const float*)d_in[0];   // [16,128,512]
    const float* dec = (const float*)d_in[1];   // [16,128,512]
    const float* W1  = (const float*)d_in[2];   // [512,512]
    const float* W2  = (const float*)d_in[3];   // [512,512]
    const float* bv  = (const float*)d_in[4];   // [512]
    const float* V   = (const float*)d_in[5];   // [512]

    float* ctx   = (float*)d_out;                           // [16,128,512] 4MB
    float* attnw = (float*)d_out + (size_t)nBt * nTq * nEd; // [16,128,128] 1MB

    // WT (2MB) in ctx region — dead before kCtxMM writes ctx.
    unsigned short* WT = (unsigned short*)d_out;

    float* ws0 = (float*)d_ws;                    // exp2((enc@W1)*PS), 4MB
    float* ws1 = ws0 + (size_t)nBt * nSq * nEd;   // exp2((dec@W2+b)*PS), 4MB
    // After kLogits, ws0 region is reused:
    unsigned short* encT   = (unsigned short*)d_ws;                        // 2MB
    unsigned short* attnbf = (unsigned short*)((char*)d_ws + 2*1024*1024); // 512KB

    kWprep<<<dim3(nEd / 32, nEd / 32, 2), dim3(256), 0, stream>>>(W1, W2, WT);
    kMgemm<<<dim3(nEd / 64, (nBt * nSq) / 64, 2), dim3(256), 0, stream>>>(
        enc, dec, WT, bv, ws0, ws1);
    kLogits<<<dim3(4, 32, nBt), dim3(256), 0, stream>>>(ws0, ws1, V, attnw);
    kEncT<<<dim3(nEd / 32, nSq / 32, nBt), dim3(256), 0, stream>>>(enc, encT);
    kSoft<<<dim3((nBt * nTq) / 4), dim3(256), 0, stream>>>(attnw, attnbf);
    kCtxMM<<<dim3(nEd / 64, nTq / 32, nBt), dim3(256), 0, stream>>>(
        attnbf, encT, ctx);
}